// Round 15
// baseline (2859.385 us; speedup 1.0000x reference)
//
#include <hip/hip_runtime.h>
#include <hip/hip_bf16.h>
#include <math.h>

// Problem constants
#define QL   1024
#define ML   1024
#define KL   2048      // QL + ML
#define DM   1024
#define NH   16
#define DH   64
#define SCL  0.125f    // 1/sqrt(64)
#define GRU_BLOCKS 128
#define GRU_ELPB   8   // hidden elements per block

typedef __attribute__((ext_vector_type(8))) short bfrag;   // 8 bf16 (4 VGPR)
typedef __attribute__((ext_vector_type(4))) float facc;    // 4 f32 acc

static __device__ __forceinline__ float dot4(const float4& a, const float4& b) {
    return a.x*b.x + a.y*b.y + a.z*b.z + a.w*b.w;
}

static __device__ __forceinline__ unsigned bf16_rne(float x) {
    unsigned u = __float_as_uint(x);
    return (u + 0x7FFF + ((u >> 16) & 1)) >> 16;
}
static __device__ __forceinline__ void bfsplit(float a, short& h, short& l) {
    unsigned uh = bf16_rne(a);
    h = (short)uh;
    float ah = __uint_as_float(uh << 16);
    l = (short)bf16_rne(a - ah);
}

// ---------------------------------------------------------------------------
// Split-bf16 MFMA NT GEMM body (math identical to R11-R14 proven version).
// NOTE: exactly 2 unconditional __syncthreads per K-step (64 total at K=1024)
// -- the fused GRU kernel's idle upper-half threads mirror this count.
// ---------------------------------------------------------------------------
static __device__ __forceinline__ void gemm_body(
    const float* __restrict__ A, const float* __restrict__ A2, int asplit,
    const float* __restrict__ B, const float* __restrict__ bias,
    float* __restrict__ C, int N, int K, int bx, int by)
{
    __shared__ short Ah[128*40], Al[128*40], Bh[128*40], Bl[128*40]; // 40KB
    const int tid = threadIdx.x;
    const int wv = tid >> 6, ln = tid & 63;
    const int wr = wv >> 1, wc = wv & 1;
    const int lm = ln & 15, lk = ln >> 4;
    facc acc[4][4] = {};

    const int srow = tid >> 1;
    const int scol = (tid & 1) << 4;
    const int arow = by*128 + srow;
    const float* Ap = ((A2 && arow >= asplit)
                        ? A2 + (size_t)(arow - asplit)*K
                        : A  + (size_t)arow*K) + scol;
    const float* Bp = B + (size_t)(bx*128 + srow)*K + scol;

    float4 ar[4], br[4];
    #pragma unroll
    for (int c = 0; c < 4; c++) {
        ar[c] = *(const float4*)(Ap + c*4);
        br[c] = *(const float4*)(Bp + c*4);
    }

    for (int k0 = 0; k0 < K; k0 += 32) {
        bfrag a_h0, a_h1, a_l0, a_l1, b_h0, b_h1, b_l0, b_l1;
        #pragma unroll
        for (int c = 0; c < 4; c++) {
            const float av[4] = {ar[c].x, ar[c].y, ar[c].z, ar[c].w};
            const float bv[4] = {br[c].x, br[c].y, br[c].z, br[c].w};
            #pragma unroll
            for (int q = 0; q < 4; q++) {
                const int e = c*4 + q;
                short h, l;
                bfsplit(av[q], h, l);
                if (e < 8) { a_h0[e] = h; a_l0[e] = l; }
                else       { a_h1[e-8] = h; a_l1[e-8] = l; }
                bfsplit(bv[q], h, l);
                if (e < 8) { b_h0[e] = h; b_l0[e] = l; }
                else       { b_h1[e-8] = h; b_l1[e-8] = l; }
            }
        }
        __syncthreads();
        *(bfrag*)&Ah[srow*40 + scol    ] = a_h0;
        *(bfrag*)&Ah[srow*40 + scol + 8] = a_h1;
        *(bfrag*)&Al[srow*40 + scol    ] = a_l0;
        *(bfrag*)&Al[srow*40 + scol + 8] = a_l1;
        *(bfrag*)&Bh[srow*40 + scol    ] = b_h0;
        *(bfrag*)&Bh[srow*40 + scol + 8] = b_h1;
        *(bfrag*)&Bl[srow*40 + scol    ] = b_l0;
        *(bfrag*)&Bl[srow*40 + scol + 8] = b_l1;
        __syncthreads();
        if (k0 + 32 < K) {
            #pragma unroll
            for (int c = 0; c < 4; c++) {
                ar[c] = *(const float4*)(Ap + k0 + 32 + c*4);
                br[c] = *(const float4*)(Bp + k0 + 32 + c*4);
            }
        }
        bfrag fah[4], fal[4], fbh[4], fbl[4];
        #pragma unroll
        for (int i = 0; i < 4; i++) {
            const int rA = wr*64 + i*16 + lm;
            fah[i] = *(const bfrag*)&Ah[rA*40 + lk*8];
            fal[i] = *(const bfrag*)&Al[rA*40 + lk*8];
            const int rB = wc*64 + i*16 + lm;
            fbh[i] = *(const bfrag*)&Bh[rB*40 + lk*8];
            fbl[i] = *(const bfrag*)&Bl[rB*40 + lk*8];
        }
        #pragma unroll
        for (int i = 0; i < 4; i++)
            #pragma unroll
            for (int j = 0; j < 4; j++) {
                acc[i][j] = __builtin_amdgcn_mfma_f32_16x16x32_bf16(fah[i], fbh[j], acc[i][j], 0, 0, 0);
                acc[i][j] = __builtin_amdgcn_mfma_f32_16x16x32_bf16(fah[i], fbl[j], acc[i][j], 0, 0, 0);
                acc[i][j] = __builtin_amdgcn_mfma_f32_16x16x32_bf16(fal[i], fbh[j], acc[i][j], 0, 0, 0);
            }
    }

    const int m0 = by*128 + wr*64 + lk*4;
    const int n0 = bx*128 + wc*64 + lm;
    #pragma unroll
    for (int j = 0; j < 4; j++) {
        const float bj = bias ? bias[n0 + j*16] : 0.f;
        #pragma unroll
        for (int i = 0; i < 4; i++)
            #pragma unroll
            for (int r = 0; r < 4; r++)
                C[(size_t)(m0 + i*16 + r)*N + n0 + j*16] = acc[i][j][r] + bj;
    }
}

// Generic wrapper (used for the Wo GEMM)
__global__ __launch_bounds__(256) void gemm_nt_mfma(
    const float* __restrict__ A, const float* __restrict__ B,
    const float* __restrict__ bias, float* __restrict__ C,
    int N, int K)
{
    gemm_body(A, nullptr, 1<<30, B, bias, C, N, K, blockIdx.x, blockIdx.y);
}

// Fused launch: blocks 0..383 = QKV GEMM ([mem;inputs] x Wqkv -> wheads),
// blocks 384..511 = r x Wr -> rk. (R14 proven, -70us.)
__global__ __launch_bounds__(256) void gemm_fused_qkv_rk(
    const float* __restrict__ mem, const float* __restrict__ inputs,
    const float* __restrict__ Wqkv, float* __restrict__ wheads,
    const float* __restrict__ r_in, const float* __restrict__ Wr,
    float* __restrict__ rk)
{
    int blk = blockIdx.x;
    if (blk < 384) {
        const int bx = blk % 24, by = blk / 24;
        if (by < 8 && bx < 8) return;          // mem rows' q-columns unused
        gemm_body(mem, inputs, 8*128, Wqkv, nullptr, wheads, 3072, DM, bx, by);
    } else {
        blk -= 384;
        const int bx = blk % 8, by = blk / 8;
        gemm_body(r_in, nullptr, 1<<30, Wr, nullptr, rk, 1024, DM, bx, by);
    }
}

// ---------------------------------------------------------------------------
// Wd[n][jr] = sum_d (v[n,d]-u[n,d]) * rk[jr, n*64+d]
// ---------------------------------------------------------------------------
__global__ __launch_bounds__(256) void wd_kernel(
    const float* __restrict__ rk, const float* __restrict__ u_,
    const float* __restrict__ v_, float* __restrict__ wd)
{
    int idx = blockIdx.x*256 + threadIdx.x;
    if (idx >= NH*KL) return;
    int n = idx >> 11, jr = idx & (KL-1);
    const float* rp = rk + (size_t)jr*DM + n*DH;
    const float* up = u_ + n*DH;
    const float* vp = v_ + n*DH;
    float s = 0.f;
    #pragma unroll
    for (int d4 = 0; d4 < 16; d4++) {
        float4 r4 = *(const float4*)(rp + d4*4);
        float4 uu = *(const float4*)(up + d4*4);
        float4 vv = *(const float4*)(vp + d4*4);
        s += (vv.x-uu.x)*r4.x + (vv.y-uu.y)*r4.y + (vv.z-uu.z)*r4.z + (vv.w-uu.w)*r4.w;
    }
    wd[idx] = s;
}

// ---------------------------------------------------------------------------
// Scores per-head 64x64 tile (unchanged)
// ---------------------------------------------------------------------------
__global__ __launch_bounds__(256) void score_kernel(
    const float* __restrict__ wh, const float* __restrict__ rk,
    const float* __restrict__ u_, const float* __restrict__ wd,
    float* __restrict__ sc)
{
    const int jt = blockIdx.x, it = blockIdx.y, n = blockIdx.z;
    const int i0 = it*64, j0 = jt*64;
    if (j0 > i0 + 1087) return;
    __shared__ float squ[64*64];
    __shared__ float sk [64*64];
    __shared__ float sr [128*64];
    __shared__ float swd[128];
    const int tid = threadIdx.x;
    #pragma unroll
    for (int rr = 0; rr < 4; rr++) {
        int p = tid + 256*rr;
        int row = p >> 4, c4 = p & 15;
        int phys = (c4 ^ ((row >> 2) & 15)) << 2;
        float4 q4 = *(const float4*)&wh[(size_t)(ML + i0 + row)*3072 + n*DH + (c4<<2)];
        float4 u4 = *(const float4*)&u_[n*DH + (c4<<2)];
        float4 t4; t4.x=q4.x+u4.x; t4.y=q4.y+u4.y; t4.z=q4.z+u4.z; t4.w=q4.w+u4.w;
        *(float4*)&squ[row*64 + phys] = t4;
        float4 k4 = *(const float4*)&wh[(size_t)(j0 + row)*3072 + DM + n*DH + (c4<<2)];
        *(float4*)&sk[row*64 + phys] = k4;
    }
    const int jr0 = j0 - i0 + 960;
    #pragma unroll
    for (int rr = 0; rr < 8; rr++) {
        int p = tid + 256*rr;
        int row = p >> 4, c4 = p & 15;
        int phys = (c4 ^ ((row >> 2) & 15)) << 2;
        int jr = jr0 + row;
        float4 r4;
        if (jr >= 0 && jr < KL) r4 = *(const float4*)&rk[(size_t)jr*DM + n*DH + (c4<<2)];
        else { r4.x = r4.y = r4.z = r4.w = 0.f; }
        *(float4*)&sr[row*64 + phys] = r4;
    }
    if (tid < 128) {
        int jr = jr0 + tid;
        swd[tid] = (jr >= 0 && jr < KL) ? wd[n*KL + jr] : 0.f;
    }
    __syncthreads();

    const int tj2 = tid & 15, ti2 = tid >> 4;
    const int rbase = tj2*4 - ti2*4 + 60;
    float acc[4][4] = {};
    #pragma unroll
    for (int dc = 0; dc < 16; dc++) {
        float4 qa[4], kb[4], rv[7];
        #pragma unroll
        for (int a = 0; a < 4; a++) {
            int row = ti2*4 + a;
            qa[a] = *(const float4*)&squ[row*64 + ((dc ^ ((row>>2)&15)) << 2)];
        }
        #pragma unroll
        for (int b_ = 0; b_ < 4; b_++) {
            int row = tj2*4 + b_;
            kb[b_] = *(const float4*)&sk[row*64 + ((dc ^ ((row>>2)&15)) << 2)];
        }
        #pragma unroll
        for (int o = 0; o < 7; o++) {
            int row = rbase + o;
            rv[o] = *(const float4*)&sr[row*64 + ((dc ^ ((row>>2)&15)) << 2)];
        }
        #pragma unroll
        for (int a = 0; a < 4; a++)
            #pragma unroll
            for (int b_ = 0; b_ < 4; b_++)
                acc[a][b_] += dot4(qa[a], kb[b_]) + dot4(qa[a], rv[3 + b_ - a]);
    }
    #pragma unroll
    for (int a = 0; a < 4; a++) {
        int i = i0 + ti2*4 + a;
        float4 o;
        o.x = (acc[a][0] + swd[rbase + 3 + 0 - a]) * SCL;
        o.y = (acc[a][1] + swd[rbase + 3 + 1 - a]) * SCL;
        o.z = (acc[a][2] + swd[rbase + 3 + 2 - a]) * SCL;
        o.w = (acc[a][3] + swd[rbase + 3 + 3 - a]) * SCL;
        *(float4*)&sc[((size_t)i*NH + n)*KL + j0 + (tj2<<2)] = o;
    }
}

// ---------------------------------------------------------------------------
// Softmax + in-place slab transpose (unchanged)
// ---------------------------------------------------------------------------
__global__ __launch_bounds__(512) void softmaxT_kernel(float* __restrict__ sc)
{
    const int i = blockIdx.x;
    const int tid = threadIdx.x;
    __shared__ float ld[16*2052];
    __shared__ float sinv[16];
    float* slab = sc + (size_t)i*KL*NH;
    #pragma unroll
    for (int rr = 0; rr < 16; rr++) {
        int p = tid + 512*rr;
        int nn = p >> 9, j = (p & 511) << 2;
        float4 f = *(const float4*)(slab + ((size_t)nn << 11) + j);
        *(float4*)&ld[nn*2052 + j] = f;
    }
    __syncthreads();
    const int g = tid >> 5, tl = tid & 31;
    const int jmax = i + ML;
    float m = -3.4e38f;
    for (int k = 0; k < 64; k++) {
        int j = tl + (k << 5);
        if (j <= jmax) m = fmaxf(m, ld[g*2052 + j]);
    }
    #pragma unroll
    for (int off = 1; off <= 16; off <<= 1) m = fmaxf(m, __shfl_xor(m, off, 64));
    float ssum = 0.f;
    for (int k = 0; k < 64; k++) {
        int j = tl + (k << 5);
        float e = 0.f;
        if (j <= jmax) { e = __expf(ld[g*2052 + j] - m); ssum += e; }
        ld[g*2052 + j] = e;
    }
    #pragma unroll
    for (int off = 1; off <= 16; off <<= 1) ssum += __shfl_xor(ssum, off, 64);
    if (tl == 0) sinv[g] = 1.f / ssum;
    __syncthreads();
    #pragma unroll
    for (int rr = 0; rr < 16; rr++) {
        int p = tid + 512*rr;
        int j = p >> 2, n0 = (p & 3) << 2;
        float4 o;
        o.x = ld[(n0+0)*2052 + j] * sinv[n0+0];
        o.y = ld[(n0+1)*2052 + j] * sinv[n0+1];
        o.z = ld[(n0+2)*2052 + j] * sinv[n0+2];
        o.w = ld[(n0+3)*2052 + j] * sinv[n0+3];
        *(float4*)(slab + (size_t)p*4) = o;
    }
}

// ---------------------------------------------------------------------------
// PV (unchanged)
// ---------------------------------------------------------------------------
__global__ __launch_bounds__(512) void pv_kernel(
    const float* __restrict__ sc, const float* __restrict__ wh,
    float* __restrict__ attn)
{
    const int it = blockIdx.x >> 1, dh = blockIdx.x & 1;
    const int i0 = it*8;
    const int tid = threadIdx.x;
    __shared__ float Ps[8*16*20];
    __shared__ float Vs[16][512];
    const int col = dh*512 + tid;
    const int nn = col >> 6;
    float acc[8] = {};
    const int jlast = i0 + 7 + ML;
    const int nch = (jlast + 16) >> 4;
    for (int ch = 0; ch < nch; ch++) {
        const int j0 = ch << 4;
        __syncthreads();
        {
            int ii = tid >> 6, rem = tid & 63, jj = rem >> 2, n0 = (rem & 3) << 2;
            float4 f = *(const float4*)(sc + ((size_t)(i0+ii)*KL + j0 + jj)*NH + n0);
            Ps[(ii*16 + n0+0)*20 + jj] = f.x;
            Ps[(ii*16 + n0+1)*20 + jj] = f.y;
            Ps[(ii*16 + n0+2)*20 + jj] = f.z;
            Ps[(ii*16 + n0+3)*20 + jj] = f.w;
        }
        #pragma unroll
        for (int rr = 0; rr < 4; rr++) {
            int p = tid + 512*rr;
            int row = p >> 7, c4 = (p & 127) << 2;
            float4 f = *(const float4*)&wh[(size_t)(j0+row)*3072 + 2048 + dh*512 + c4];
            *(float4*)&Vs[row][c4] = f;
        }
        __syncthreads();
        #pragma unroll
        for (int jq = 0; jq < 4; jq++) {
            float4 pv[8];
            #pragma unroll
            for (int ii = 0; ii < 8; ii++)
                pv[ii] = *(const float4*)&Ps[(ii*16 + nn)*20 + jq*4];
            #pragma unroll
            for (int jj = 0; jj < 4; jj++) {
                float vv = Vs[jq*4 + jj][tid];
                #pragma unroll
                for (int ii = 0; ii < 8; ii++)
                    acc[ii] += ((const float*)&pv[ii])[jj] * vv;
            }
        }
    }
    #pragma unroll
    for (int ii = 0; ii < 8; ii++)
        attn[(size_t)(i0+ii)*DM + col] = acc[ii];
}

// ---------------------------------------------------------------------------
// FUSED xproj GEMM + persistent GRU (producer-consumer in ONE dispatch).
// Blocks 0..127: GRU (placed first -> all co-resident; proven v6 structure).
// Blocks 128..319: xproj tiles, 512 threads (upper half idles through the
// matching 64-barrier sequence). Tile completion published per row-group via
// RELEASE fetch_add on xdone[by] (flushes writer L2); GRU lane-0 gates its
// x-loads on a watermark: relaxed poll + ONE acquire fence per 128-step
// boundary (8 total). GRU consumes rows at ~2us each -- GEMM (~40-80us
// total) stays entirely ahead after the first gate.
// ---------------------------------------------------------------------------
__global__ __launch_bounds__(512) void gru_xproj_fused(
    const float* __restrict__ ybuf,  // [1024][1024]
    const float* __restrict__ Wih,   // [3072][1024]
    const float* __restrict__ bih,   // [3072]
    float* __restrict__ xproj,       // ws [1024][3072]
    const float* __restrict__ Whh,   // [3072][1024]
    const float* __restrict__ bhh,   // [3072]
    const float* __restrict__ h0,    // [1024]
    float* __restrict__ ys,          // d_out [1024][1024]
    unsigned long long* __restrict__ hpack,  // ws [2][1024], memset 0
    unsigned* __restrict__ xdone)    // ws [8], memset 0
{
    const int blk = blockIdx.x;
    const int tid = threadIdx.x;

    if (blk >= GRU_BLOCKS) {
        // ---- xproj GEMM producer ----
        const int gblk = blk - GRU_BLOCKS;
        const int bx = gblk % 24, by = gblk / 24;
        if (tid < 256) {
            gemm_body(ybuf, nullptr, 1<<30, Wih, bih, xproj, 3072, DM, bx, by);
        } else {
            for (int k0 = 0; k0 < DM; k0 += 32) { __syncthreads(); __syncthreads(); }
        }
        __syncthreads();   // drain all threads' C stores (vmcnt0 at barrier)
        if (tid == 0)
            __hip_atomic_fetch_add(&xdone[by], 1u, __ATOMIC_RELEASE,
                                   __HIP_MEMORY_SCOPE_AGENT);
        return;
    }

    // ---- GRU consumer (proven v6/v10 structure) ----
    __shared__ float wlds[3][GRU_ELPB][DM];   // 98304 B
    __shared__ float hlds[DM];                //  4096 B
    const int b = blk;
    const int w = tid >> 6, l = tid & 63;     // 8 waves; wave w -> elem b*8+w
    const int dg = b*GRU_ELPB + w;

    #pragma unroll
    for (int k = 0; k < 12; k++) {
        int idx = tid + 512*k;            // float4 index
        int g   = idx >> 11;
        int rem = idx & 2047;
        int e   = rem >> 8;
        int c   = rem & 255;
        float4 f = *(const float4*)&Whh[(size_t)(g*DM + b*GRU_ELPB + e)*DM + (c<<2)];
        *(float4*)&wlds[g][e][c<<2] = f;
    }
    float bh0=0.f, bh1=0.f, bh2=0.f, hreg=0.f;
    if (l == 0) {
        bh0 = bhh[dg]; bh1 = bhh[dg + DM]; bh2 = bhh[dg + 2*DM];
        hreg = h0[dg];
    }

    bool bail = false;
    int ready_by = -1;   // watermark: highest xproj row-group known complete
    for (int t = 0; t < QL; t++) {
        const int need = t >> 7;
        if (need > ready_by) {
            if (l == 0) {
                int guard = 0;
                while (__hip_atomic_load(&xdone[need], __ATOMIC_RELAXED,
                                         __HIP_MEMORY_SCOPE_AGENT) < 24u) {
                    if (++guard > (1<<18)) break;
                }
                __builtin_amdgcn_fence(__ATOMIC_ACQUIRE, "agent");
            }
            ready_by = need;
        }
        float xr=0.f, xz=0.f, xn=0.f;
        if (l == 0) {   // gated above: rows [need*128, ...) are published
            const float* xrow = xproj + (size_t)t*3072 + dg;
            xr = xrow[0]; xz = xrow[DM]; xn = xrow[2*DM];
        }
        if (t == 0) {
            hlds[tid]       = h0[tid];
            hlds[tid + 512] = h0[tid + 512];
        } else if (!bail) {
            const unsigned long long* hp = hpack + ((size_t)(t & 1) << 10);
            unsigned long long v0 = 0, v1 = 0;
            bool d0 = false, d1 = false;
            int guard = 0;
            for (;;) {
                if (!d0) { v0 = __hip_atomic_load(&hp[tid],       __ATOMIC_RELAXED, __HIP_MEMORY_SCOPE_AGENT);
                           d0 = (unsigned)(v0 >> 32) >= (unsigned)t; }
                if (!d1) { v1 = __hip_atomic_load(&hp[tid + 512], __ATOMIC_RELAXED, __HIP_MEMORY_SCOPE_AGENT);
                           d1 = (unsigned)(v1 >> 32) >= (unsigned)t; }
                if (d0 && d1) break;
                if (++guard > (1<<18)) { bail = true; break; }
            }
            hlds[tid]       = __uint_as_float((unsigned)v0);
            hlds[tid + 512] = __uint_as_float((unsigned)v1);
        }
        __syncthreads();   // hlds ready (the ONLY barrier per step)

        // conflict-free matvec: lane l covers cols {c*256 + l*4 .. +3}
        float s0=0.f, s1=0.f, s2=0.f;
        #pragma unroll
        for (int c = 0; c < 4; c++) {
            const int base = c*256 + l*4;
            float4 h4 = *(const float4*)&hlds[base];
            float4 w0 = *(const float4*)&wlds[0][w][base];
            float4 w1 = *(const float4*)&wlds[1][w][base];
            float4 w2 = *(const float4*)&wlds[2][w][base];
            s0 += dot4(w0, h4);
            s1 += dot4(w1, h4);
            s2 += dot4(w2, h4);
        }
        #pragma unroll
        for (int off = 32; off >= 1; off >>= 1) {
            s0 += __shfl_xor(s0, off, 64);
            s1 += __shfl_xor(s1, off, 64);
            s2 += __shfl_xor(s2, off, 64);
        }
        if (l == 0) {
            const float hr = s0 + bh0;
            const float hz = s1 + bh1;
            const float hn = s2 + bh2;
            const float rg = 1.f/(1.f + __expf(-(xr + hr)));
            const float zg = 1.f/(1.f + __expf(-(xz + hz)));
            const float e2 = __expf(2.f*(xn + rg*hn));       // fast tanh
            const float ng = (e2 - 1.f) / (e2 + 1.f);
            const float hnew = (1.f - zg)*ng + zg*hreg;
            hreg = hnew;
            unsigned long long pk = (unsigned long long)__float_as_uint(hnew)
                                  | ((unsigned long long)(unsigned)(t+1) << 32);
            __hip_atomic_store(&hpack[(((size_t)(t+1) & 1) << 10) + dg], pk,
                               __ATOMIC_RELAXED, __HIP_MEMORY_SCOPE_AGENT);
            ys[(size_t)t*DM + dg] = hnew;
        }
    }
}

// ---------------------------------------------------------------------------
extern "C" void kernel_launch(void* const* d_in, const int* in_sizes, int n_in,
                              void* d_out, int out_size, void* d_ws, size_t ws_size,
                              hipStream_t stream) {
    const float* inputs = (const float*)d_in[0];   // [1024,1,1024]
    const float* r_in   = (const float*)d_in[1];   // [2048,1024]
    const float* u_in   = (const float*)d_in[2];   // [16,64]
    const float* v_in   = (const float*)d_in[3];   // [16,64]
    // d_in[4] = attn_mask (bool) -- computed analytically, unused
    const float* mem    = (const float*)d_in[5];   // [1024,1,1024]
    const float* Wqkv   = (const float*)d_in[6];   // [3072,1024]
    const float* Wr     = (const float*)d_in[7];   // [1024,1024]
    const float* Wo     = (const float*)d_in[8];   // [1024,1024]
    const float* Wih    = (const float*)d_in[9];   // [3072,1024]
    const float* Whh    = (const float*)d_in[10];  // [3072,1024]
    const float* b_ih   = (const float*)d_in[11];  // [3072]
    const float* b_hh   = (const float*)d_in[12];  // [3072]
    const float* h0     = (const float*)d_in[13];  // [1,1,1024]

    float* out = (float*)d_out;
    float* ys  = out;                    // [1024][1024]
    float* sc  = out + (size_t)QL*DM;    // probs region

    float* ws      = (float*)d_ws;
    float* cat     = ws;                                  // 2048*1024 (unused)
    float* wheads  = cat    + (size_t)KL*DM;              // 2048*3072
    float* rk      = wheads + (size_t)KL*3072;            // 2048*1024
    float* wd      = rk     + (size_t)KL*DM;              // 16*2048
    float* attn    = wd     + (size_t)NH*KL;              // 1024*1024
    float* ybuf    = attn   + (size_t)QL*DM;              // 1024*1024
    float* xproj   = ybuf   + (size_t)QL*DM;              // 1024*3072
    unsigned long long* hpack = (unsigned long long*)(xproj + (size_t)QL*3072); // [2][1024]
    unsigned* xdone = (unsigned*)(hpack + 2*DM);          // [8]

    hipMemsetAsync(hpack, 0, 2*DM*sizeof(unsigned long long) + 8*sizeof(unsigned), stream);

    gemm_fused_qkv_rk<<<512, 256, 0, stream>>>(mem, inputs, Wqkv, wheads, r_in, Wr, rk);
    wd_kernel<<<128, 256, 0, stream>>>(rk, u_in, v_in, wd);
    score_kernel<<<dim3(32,16,16), 256, 0, stream>>>(wheads, rk, u_in, wd, sc);
    softmaxT_kernel<<<QL, 512, 0, stream>>>(sc);
    pv_kernel<<<256, 512, 0, stream>>>(sc, wheads, attn);
    gemm_nt_mfma<<<dim3(8,8), 256, 0, stream>>>(attn, Wo, nullptr, ybuf, DM, DM);
    gru_xproj_fused<<<GRU_BLOCKS + 192, 512, 0, stream>>>(
        ybuf, Wih, b_ih, xproj, Whh, b_hh, h0, ys, hpack, xdone);
}

// Round 16
// 2812.474 us; speedup vs baseline: 1.0167x; 1.0167x over previous
//
#include <hip/hip_runtime.h>
#include <hip/hip_bf16.h>
#include <math.h>

// Problem constants
#define QL   1024
#define ML   1024
#define KL   2048      // QL + ML
#define DM   1024
#define NH   16
#define DH   64
#define SCL  0.125f    // 1/sqrt(64)
#define GRU_BLOCKS 128
#define GRU_ELPB   8   // hidden elements per block

typedef __attribute__((ext_vector_type(8))) short bfrag;   // 8 bf16 (4 VGPR)
typedef __attribute__((ext_vector_type(4))) float facc;    // 4 f32 acc

static __device__ __forceinline__ float dot4(const float4& a, const float4& b) {
    return a.x*b.x + a.y*b.y + a.z*b.z + a.w*b.w;
}

static __device__ __forceinline__ unsigned bf16_rne(float x) {
    unsigned u = __float_as_uint(x);
    return (u + 0x7FFF + ((u >> 16) & 1)) >> 16;
}
static __device__ __forceinline__ void bfsplit(float a, short& h, short& l) {
    unsigned uh = bf16_rne(a);
    h = (short)uh;
    float ah = __uint_as_float(uh << 16);
    l = (short)bf16_rne(a - ah);
}

// ---------------------------------------------------------------------------
// Split-bf16 MFMA NT GEMM body (R11-proven math; R14-proven config).
// ---------------------------------------------------------------------------
static __device__ __forceinline__ void gemm_body(
    const float* __restrict__ A, const float* __restrict__ A2, int asplit,
    const float* __restrict__ B, const float* __restrict__ bias,
    float* __restrict__ C, int N, int K, int bx, int by)
{
    __shared__ short Ah[128*40], Al[128*40], Bh[128*40], Bl[128*40]; // 40KB
    const int tid = threadIdx.x;
    const int wv = tid >> 6, ln = tid & 63;
    const int wr = wv >> 1, wc = wv & 1;
    const int lm = ln & 15, lk = ln >> 4;
    facc acc[4][4] = {};

    const int srow = tid >> 1;
    const int scol = (tid & 1) << 4;
    const int arow = by*128 + srow;
    const float* Ap = ((A2 && arow >= asplit)
                        ? A2 + (size_t)(arow - asplit)*K
                        : A  + (size_t)arow*K) + scol;
    const float* Bp = B + (size_t)(bx*128 + srow)*K + scol;

    float4 ar[4], br[4];
    #pragma unroll
    for (int c = 0; c < 4; c++) {
        ar[c] = *(const float4*)(Ap + c*4);
        br[c] = *(const float4*)(Bp + c*4);
    }

    for (int k0 = 0; k0 < K; k0 += 32) {
        bfrag a_h0, a_h1, a_l0, a_l1, b_h0, b_h1, b_l0, b_l1;
        #pragma unroll
        for (int c = 0; c < 4; c++) {
            const float av[4] = {ar[c].x, ar[c].y, ar[c].z, ar[c].w};
            const float bv[4] = {br[c].x, br[c].y, br[c].z, br[c].w};
            #pragma unroll
            for (int q = 0; q < 4; q++) {
                const int e = c*4 + q;
                short h, l;
                bfsplit(av[q], h, l);
                if (e < 8) { a_h0[e] = h; a_l0[e] = l; }
                else       { a_h1[e-8] = h; a_l1[e-8] = l; }
                bfsplit(bv[q], h, l);
                if (e < 8) { b_h0[e] = h; b_l0[e] = l; }
                else       { b_h1[e-8] = h; b_l1[e-8] = l; }
            }
        }
        __syncthreads();
        *(bfrag*)&Ah[srow*40 + scol    ] = a_h0;
        *(bfrag*)&Ah[srow*40 + scol + 8] = a_h1;
        *(bfrag*)&Al[srow*40 + scol    ] = a_l0;
        *(bfrag*)&Al[srow*40 + scol + 8] = a_l1;
        *(bfrag*)&Bh[srow*40 + scol    ] = b_h0;
        *(bfrag*)&Bh[srow*40 + scol + 8] = b_h1;
        *(bfrag*)&Bl[srow*40 + scol    ] = b_l0;
        *(bfrag*)&Bl[srow*40 + scol + 8] = b_l1;
        __syncthreads();
        if (k0 + 32 < K) {
            #pragma unroll
            for (int c = 0; c < 4; c++) {
                ar[c] = *(const float4*)(Ap + k0 + 32 + c*4);
                br[c] = *(const float4*)(Bp + k0 + 32 + c*4);
            }
        }
        bfrag fah[4], fal[4], fbh[4], fbl[4];
        #pragma unroll
        for (int i = 0; i < 4; i++) {
            const int rA = wr*64 + i*16 + lm;
            fah[i] = *(const bfrag*)&Ah[rA*40 + lk*8];
            fal[i] = *(const bfrag*)&Al[rA*40 + lk*8];
            const int rB = wc*64 + i*16 + lm;
            fbh[i] = *(const bfrag*)&Bh[rB*40 + lk*8];
            fbl[i] = *(const bfrag*)&Bl[rB*40 + lk*8];
        }
        #pragma unroll
        for (int i = 0; i < 4; i++)
            #pragma unroll
            for (int j = 0; j < 4; j++) {
                acc[i][j] = __builtin_amdgcn_mfma_f32_16x16x32_bf16(fah[i], fbh[j], acc[i][j], 0, 0, 0);
                acc[i][j] = __builtin_amdgcn_mfma_f32_16x16x32_bf16(fah[i], fbl[j], acc[i][j], 0, 0, 0);
                acc[i][j] = __builtin_amdgcn_mfma_f32_16x16x32_bf16(fal[i], fbh[j], acc[i][j], 0, 0, 0);
            }
    }

    const int m0 = by*128 + wr*64 + lk*4;
    const int n0 = bx*128 + wc*64 + lm;
    #pragma unroll
    for (int j = 0; j < 4; j++) {
        const float bj = bias ? bias[n0 + j*16] : 0.f;
        #pragma unroll
        for (int i = 0; i < 4; i++)
            #pragma unroll
            for (int r = 0; r < 4; r++)
                C[(size_t)(m0 + i*16 + r)*N + n0 + j*16] = acc[i][j][r] + bj;
    }
}

// Generic wrapper (used for Wo and Wih GEMMs)
__global__ __launch_bounds__(256) void gemm_nt_mfma(
    const float* __restrict__ A, const float* __restrict__ B,
    const float* __restrict__ bias, float* __restrict__ C,
    int N, int K)
{
    gemm_body(A, nullptr, 1<<30, B, bias, C, N, K, blockIdx.x, blockIdx.y);
}

// Fused launch: blocks 0..383 = QKV GEMM ([mem;inputs] x Wqkv -> wheads),
// blocks 384..511 = r x Wr -> rk. (R14 proven, -70us.)
__global__ __launch_bounds__(256) void gemm_fused_qkv_rk(
    const float* __restrict__ mem, const float* __restrict__ inputs,
    const float* __restrict__ Wqkv, float* __restrict__ wheads,
    const float* __restrict__ r_in, const float* __restrict__ Wr,
    float* __restrict__ rk)
{
    int blk = blockIdx.x;
    if (blk < 384) {
        const int bx = blk % 24, by = blk / 24;
        if (by < 8 && bx < 8) return;          // mem rows' q-columns unused
        gemm_body(mem, inputs, 8*128, Wqkv, nullptr, wheads, 3072, DM, bx, by);
    } else {
        blk -= 384;
        const int bx = blk % 8, by = blk / 8;
        gemm_body(r_in, nullptr, 1<<30, Wr, nullptr, rk, 1024, DM, bx, by);
    }
}

// ---------------------------------------------------------------------------
// Wd[n][jr] = sum_d (v[n,d]-u[n,d]) * rk[jr, n*64+d]
// ---------------------------------------------------------------------------
__global__ __launch_bounds__(256) void wd_kernel(
    const float* __restrict__ rk, const float* __restrict__ u_,
    const float* __restrict__ v_, float* __restrict__ wd)
{
    int idx = blockIdx.x*256 + threadIdx.x;
    if (idx >= NH*KL) return;
    int n = idx >> 11, jr = idx & (KL-1);
    const float* rp = rk + (size_t)jr*DM + n*DH;
    const float* up = u_ + n*DH;
    const float* vp = v_ + n*DH;
    float s = 0.f;
    #pragma unroll
    for (int d4 = 0; d4 < 16; d4++) {
        float4 r4 = *(const float4*)(rp + d4*4);
        float4 uu = *(const float4*)(up + d4*4);
        float4 vv = *(const float4*)(vp + d4*4);
        s += (vv.x-uu.x)*r4.x + (vv.y-uu.y)*r4.y + (vv.z-uu.z)*r4.z + (vv.w-uu.w)*r4.w;
    }
    wd[idx] = s;
}

// ---------------------------------------------------------------------------
// Scores per-head 64x64 tile (unchanged)
// ---------------------------------------------------------------------------
__global__ __launch_bounds__(256) void score_kernel(
    const float* __restrict__ wh, const float* __restrict__ rk,
    const float* __restrict__ u_, const float* __restrict__ wd,
    float* __restrict__ sc)
{
    const int jt = blockIdx.x, it = blockIdx.y, n = blockIdx.z;
    const int i0 = it*64, j0 = jt*64;
    if (j0 > i0 + 1087) return;
    __shared__ float squ[64*64];
    __shared__ float sk [64*64];
    __shared__ float sr [128*64];
    __shared__ float swd[128];
    const int tid = threadIdx.x;
    #pragma unroll
    for (int rr = 0; rr < 4; rr++) {
        int p = tid + 256*rr;
        int row = p >> 4, c4 = p & 15;
        int phys = (c4 ^ ((row >> 2) & 15)) << 2;
        float4 q4 = *(const float4*)&wh[(size_t)(ML + i0 + row)*3072 + n*DH + (c4<<2)];
        float4 u4 = *(const float4*)&u_[n*DH + (c4<<2)];
        float4 t4; t4.x=q4.x+u4.x; t4.y=q4.y+u4.y; t4.z=q4.z+u4.z; t4.w=q4.w+u4.w;
        *(float4*)&squ[row*64 + phys] = t4;
        float4 k4 = *(const float4*)&wh[(size_t)(j0 + row)*3072 + DM + n*DH + (c4<<2)];
        *(float4*)&sk[row*64 + phys] = k4;
    }
    const int jr0 = j0 - i0 + 960;
    #pragma unroll
    for (int rr = 0; rr < 8; rr++) {
        int p = tid + 256*rr;
        int row = p >> 4, c4 = p & 15;
        int phys = (c4 ^ ((row >> 2) & 15)) << 2;
        int jr = jr0 + row;
        float4 r4;
        if (jr >= 0 && jr < KL) r4 = *(const float4*)&rk[(size_t)jr*DM + n*DH + (c4<<2)];
        else { r4.x = r4.y = r4.z = r4.w = 0.f; }
        *(float4*)&sr[row*64 + phys] = r4;
    }
    if (tid < 128) {
        int jr = jr0 + tid;
        swd[tid] = (jr >= 0 && jr < KL) ? wd[n*KL + jr] : 0.f;
    }
    __syncthreads();

    const int tj2 = tid & 15, ti2 = tid >> 4;
    const int rbase = tj2*4 - ti2*4 + 60;
    float acc[4][4] = {};
    #pragma unroll
    for (int dc = 0; dc < 16; dc++) {
        float4 qa[4], kb[4], rv[7];
        #pragma unroll
        for (int a = 0; a < 4; a++) {
            int row = ti2*4 + a;
            qa[a] = *(const float4*)&squ[row*64 + ((dc ^ ((row>>2)&15)) << 2)];
        }
        #pragma unroll
        for (int b_ = 0; b_ < 4; b_++) {
            int row = tj2*4 + b_;
            kb[b_] = *(const float4*)&sk[row*64 + ((dc ^ ((row>>2)&15)) << 2)];
        }
        #pragma unroll
        for (int o = 0; o < 7; o++) {
            int row = rbase + o;
            rv[o] = *(const float4*)&sr[row*64 + ((dc ^ ((row>>2)&15)) << 2)];
        }
        #pragma unroll
        for (int a = 0; a < 4; a++)
            #pragma unroll
            for (int b_ = 0; b_ < 4; b_++)
                acc[a][b_] += dot4(qa[a], kb[b_]) + dot4(qa[a], rv[3 + b_ - a]);
    }
    #pragma unroll
    for (int a = 0; a < 4; a++) {
        int i = i0 + ti2*4 + a;
        float4 o;
        o.x = (acc[a][0] + swd[rbase + 3 + 0 - a]) * SCL;
        o.y = (acc[a][1] + swd[rbase + 3 + 1 - a]) * SCL;
        o.z = (acc[a][2] + swd[rbase + 3 + 2 - a]) * SCL;
        o.w = (acc[a][3] + swd[rbase + 3 + 3 - a]) * SCL;
        *(float4*)&sc[((size_t)i*NH + n)*KL + j0 + (tj2<<2)] = o;
    }
}

// ---------------------------------------------------------------------------
// Softmax + in-place slab transpose (unchanged)
// ---------------------------------------------------------------------------
__global__ __launch_bounds__(512) void softmaxT_kernel(float* __restrict__ sc)
{
    const int i = blockIdx.x;
    const int tid = threadIdx.x;
    __shared__ float ld[16*2052];
    __shared__ float sinv[16];
    float* slab = sc + (size_t)i*KL*NH;
    #pragma unroll
    for (int rr = 0; rr < 16; rr++) {
        int p = tid + 512*rr;
        int nn = p >> 9, j = (p & 511) << 2;
        float4 f = *(const float4*)(slab + ((size_t)nn << 11) + j);
        *(float4*)&ld[nn*2052 + j] = f;
    }
    __syncthreads();
    const int g = tid >> 5, tl = tid & 31;
    const int jmax = i + ML;
    float m = -3.4e38f;
    for (int k = 0; k < 64; k++) {
        int j = tl + (k << 5);
        if (j <= jmax) m = fmaxf(m, ld[g*2052 + j]);
    }
    #pragma unroll
    for (int off = 1; off <= 16; off <<= 1) m = fmaxf(m, __shfl_xor(m, off, 64));
    float ssum = 0.f;
    for (int k = 0; k < 64; k++) {
        int j = tl + (k << 5);
        float e = 0.f;
        if (j <= jmax) { e = __expf(ld[g*2052 + j] - m); ssum += e; }
        ld[g*2052 + j] = e;
    }
    #pragma unroll
    for (int off = 1; off <= 16; off <<= 1) ssum += __shfl_xor(ssum, off, 64);
    if (tl == 0) sinv[g] = 1.f / ssum;
    __syncthreads();
    #pragma unroll
    for (int rr = 0; rr < 16; rr++) {
        int p = tid + 512*rr;
        int j = p >> 2, n0 = (p & 3) << 2;
        float4 o;
        o.x = ld[(n0+0)*2052 + j] * sinv[n0+0];
        o.y = ld[(n0+1)*2052 + j] * sinv[n0+1];
        o.z = ld[(n0+2)*2052 + j] * sinv[n0+2];
        o.w = ld[(n0+3)*2052 + j] * sinv[n0+3];
        *(float4*)(slab + (size_t)p*4) = o;
    }
}

// ---------------------------------------------------------------------------
// PV (unchanged)
// ---------------------------------------------------------------------------
__global__ __launch_bounds__(512) void pv_kernel(
    const float* __restrict__ sc, const float* __restrict__ wh,
    float* __restrict__ attn)
{
    const int it = blockIdx.x >> 1, dh = blockIdx.x & 1;
    const int i0 = it*8;
    const int tid = threadIdx.x;
    __shared__ float Ps[8*16*20];
    __shared__ float Vs[16][512];
    const int col = dh*512 + tid;
    const int nn = col >> 6;
    float acc[8] = {};
    const int jlast = i0 + 7 + ML;
    const int nch = (jlast + 16) >> 4;
    for (int ch = 0; ch < nch; ch++) {
        const int j0 = ch << 4;
        __syncthreads();
        {
            int ii = tid >> 6, rem = tid & 63, jj = rem >> 2, n0 = (rem & 3) << 2;
            float4 f = *(const float4*)(sc + ((size_t)(i0+ii)*KL + j0 + jj)*NH + n0);
            Ps[(ii*16 + n0+0)*20 + jj] = f.x;
            Ps[(ii*16 + n0+1)*20 + jj] = f.y;
            Ps[(ii*16 + n0+2)*20 + jj] = f.z;
            Ps[(ii*16 + n0+3)*20 + jj] = f.w;
        }
        #pragma unroll
        for (int rr = 0; rr < 4; rr++) {
            int p = tid + 512*rr;
            int row = p >> 7, c4 = (p & 127) << 2;
            float4 f = *(const float4*)&wh[(size_t)(j0+row)*3072 + 2048 + dh*512 + c4];
            *(float4*)&Vs[row][c4] = f;
        }
        __syncthreads();
        #pragma unroll
        for (int jq = 0; jq < 4; jq++) {
            float4 pv[8];
            #pragma unroll
            for (int ii = 0; ii < 8; ii++)
                pv[ii] = *(const float4*)&Ps[(ii*16 + nn)*20 + jq*4];
            #pragma unroll
            for (int jj = 0; jj < 4; jj++) {
                float vv = Vs[jq*4 + jj][tid];
                #pragma unroll
                for (int ii = 0; ii < 8; ii++)
                    acc[ii] += ((const float*)&pv[ii])[jj] * vv;
            }
        }
    }
    #pragma unroll
    for (int ii = 0; ii < 8; ii++)
        attn[(size_t)(i0+ii)*DM + col] = acc[ii];
}

// ---------------------------------------------------------------------------
// Persistent GRU (frozen v6/v10 design -- 1.98ms measured structural floor;
// R15 lesson: must run ISOLATED -- co-resident GEMM blocks inflate the
// latency-critical step chain by more than any fusion saves).
// ---------------------------------------------------------------------------
__global__ __launch_bounds__(512) void gru_persistent(
    const float* __restrict__ xp,   // [1024][3072] = x@W_ih^T + b_ih
    const float* __restrict__ Whh,  // [3072][1024]
    const float* __restrict__ bhh,  // [3072]
    const float* __restrict__ h0,   // [1024]
    float* __restrict__ ys,         // d_out [1024][1024]
    unsigned long long* __restrict__ hpack)  // ws [2][1024], memset 0
{
    __shared__ float wlds[3][GRU_ELPB][DM];   // 98304 B
    __shared__ float hlds[DM];                //  4096 B
    const int b = blockIdx.x;
    const int tid = threadIdx.x;
    const int w = tid >> 6, l = tid & 63;     // 8 waves; wave w -> elem b*8+w
    const int dg = b*GRU_ELPB + w;

    #pragma unroll
    for (int k = 0; k < 12; k++) {
        int idx = tid + 512*k;            // float4 index
        int g   = idx >> 11;
        int rem = idx & 2047;
        int e   = rem >> 8;
        int c   = rem & 255;
        float4 f = *(const float4*)&Whh[(size_t)(g*DM + b*GRU_ELPB + e)*DM + (c<<2)];
        *(float4*)&wlds[g][e][c<<2] = f;
    }
    float bh0=0.f, bh1=0.f, bh2=0.f, hreg=0.f;
    if (l == 0) {
        bh0 = bhh[dg]; bh1 = bhh[dg + DM]; bh2 = bhh[dg + 2*DM];
        hreg = h0[dg];
    }

    bool bail = false;
    for (int t = 0; t < QL; t++) {
        float xr=0.f, xz=0.f, xn=0.f;
        if (l == 0) {   // immutable input: issue before the poll
            const float* xrow = xp + (size_t)t*3072 + dg;
            xr = xrow[0]; xz = xrow[DM]; xn = xrow[2*DM];
        }
        if (t == 0) {
            hlds[tid]       = h0[tid];
            hlds[tid + 512] = h0[tid + 512];
        } else if (!bail) {
            const unsigned long long* hp = hpack + ((size_t)(t & 1) << 10);
            unsigned long long v0 = 0, v1 = 0;
            bool d0 = false, d1 = false;
            int guard = 0;
            for (;;) {
                if (!d0) { v0 = __hip_atomic_load(&hp[tid],       __ATOMIC_RELAXED, __HIP_MEMORY_SCOPE_AGENT);
                           d0 = (unsigned)(v0 >> 32) >= (unsigned)t; }
                if (!d1) { v1 = __hip_atomic_load(&hp[tid + 512], __ATOMIC_RELAXED, __HIP_MEMORY_SCOPE_AGENT);
                           d1 = (unsigned)(v1 >> 32) >= (unsigned)t; }
                if (d0 && d1) break;
                if (++guard > (1<<18)) { bail = true; break; }
            }
            hlds[tid]       = __uint_as_float((unsigned)v0);
            hlds[tid + 512] = __uint_as_float((unsigned)v1);
        }
        __syncthreads();   // hlds ready (the ONLY barrier per step)

        // conflict-free matvec: lane l covers cols {c*256 + l*4 .. +3}
        float s0=0.f, s1=0.f, s2=0.f;
        #pragma unroll
        for (int c = 0; c < 4; c++) {
            const int base = c*256 + l*4;
            float4 h4 = *(const float4*)&hlds[base];
            float4 w0 = *(const float4*)&wlds[0][w][base];
            float4 w1 = *(const float4*)&wlds[1][w][base];
            float4 w2 = *(const float4*)&wlds[2][w][base];
            s0 += dot4(w0, h4);
            s1 += dot4(w1, h4);
            s2 += dot4(w2, h4);
        }
        #pragma unroll
        for (int off = 32; off >= 1; off >>= 1) {
            s0 += __shfl_xor(s0, off, 64);
            s1 += __shfl_xor(s1, off, 64);
            s2 += __shfl_xor(s2, off, 64);
        }
        if (l == 0) {
            const float hr = s0 + bh0;
            const float hz = s1 + bh1;
            const float hn = s2 + bh2;
            const float rg = 1.f/(1.f + __expf(-(xr + hr)));
            const float zg = 1.f/(1.f + __expf(-(xz + hz)));
            const float e2 = __expf(2.f*(xn + rg*hn));       // fast tanh
            const float ng = (e2 - 1.f) / (e2 + 1.f);
            const float hnew = (1.f - zg)*ng + zg*hreg;
            hreg = hnew;
            unsigned long long pk = (unsigned long long)__float_as_uint(hnew)
                                  | ((unsigned long long)(unsigned)(t+1) << 32);
            __hip_atomic_store(&hpack[(((size_t)(t+1) & 1) << 10) + dg], pk,
                               __ATOMIC_RELAXED, __HIP_MEMORY_SCOPE_AGENT);
            ys[(size_t)t*DM + dg] = hnew;
        }
    }
}

// ---------------------------------------------------------------------------
extern "C" void kernel_launch(void* const* d_in, const int* in_sizes, int n_in,
                              void* d_out, int out_size, void* d_ws, size_t ws_size,
                              hipStream_t stream) {
    const float* inputs = (const float*)d_in[0];   // [1024,1,1024]
    const float* r_in   = (const float*)d_in[1];   // [2048,1024]
    const float* u_in   = (const float*)d_in[2];   // [16,64]
    const float* v_in   = (const float*)d_in[3];   // [16,64]
    // d_in[4] = attn_mask (bool) -- computed analytically, unused
    const float* mem    = (const float*)d_in[5];   // [1024,1,1024]
    const float* Wqkv   = (const float*)d_in[6];   // [3072,1024]
    const float* Wr     = (const float*)d_in[7];   // [1024,1024]
    const float* Wo     = (const float*)d_in[8];   // [1024,1024]
    const float* Wih    = (const float*)d_in[9];   // [3072,1024]
    const float* Whh    = (const float*)d_in[10];  // [3072,1024]
    const float* b_ih   = (const float*)d_in[11];  // [3072]
    const float* b_hh   = (const float*)d_in[12];  // [3072]
    const float* h0     = (const float*)d_in[13];  // [1,1,1024]

    float* out = (float*)d_out;
    float* ys  = out;                    // [1024][1024]
    float* sc  = out + (size_t)QL*DM;    // probs region

    float* ws      = (float*)d_ws;
    float* cat     = ws;                                  // 2048*1024 (unused)
    float* wheads  = cat    + (size_t)KL*DM;              // 2048*3072
    float* rk      = wheads + (size_t)KL*3072;            // 2048*1024
    float* wd      = rk     + (size_t)KL*DM;              // 16*2048
    float* attn    = wd     + (size_t)NH*KL;              // 1024*1024
    float* ybuf    = attn   + (size_t)QL*DM;              // 1024*1024
    float* xproj   = ybuf   + (size_t)QL*DM;              // 1024*3072
    unsigned long long* hpack = (unsigned long long*)(xproj + (size_t)QL*3072); // [2][1024]

    hipMemsetAsync(hpack, 0, 2*DM*sizeof(unsigned long long), stream);

    // fused: QKV GEMM (concat folded in) + rk GEMM, one dispatch
    gemm_fused_qkv_rk<<<512, 256, 0, stream>>>(mem, inputs, Wqkv, wheads, r_in, Wr, rk);
    wd_kernel<<<128, 256, 0, stream>>>(rk, u_in, v_in, wd);
    score_kernel<<<dim3(32,16,16), 256, 0, stream>>>(wheads, rk, u_in, wd, sc);
    softmaxT_kernel<<<QL, 512, 0, stream>>>(sc);
    pv_kernel<<<256, 512, 0, stream>>>(sc, wheads, attn);
    gemm_nt_mfma<<<dim3(8,8), 256, 0, stream>>>(attn, Wo, nullptr, ybuf, DM, DM);
    gemm_nt_mfma<<<dim3(24,8), 256, 0, stream>>>(ybuf, Wih, b_ih, xproj, 3072, DM);
    gru_persistent<<<GRU_BLOCKS, 512, 0, stream>>>(xproj, Whh, b_hh, h0, ys, hpack);
}